// Round 1
// baseline (390.236 us; speedup 1.0000x reference)
//
#include <hip/hip_runtime.h>
#include <math.h>

// ---------------- types / helpers ----------------
typedef float f32x4 __attribute__((ext_vector_type(4)));
typedef __bf16 bf16x4 __attribute__((ext_vector_type(4)));
typedef __bf16 bf16x8 __attribute__((ext_vector_type(8)));

union FragU { bf16x8 v; bf16x4 h[2]; };

__device__ __forceinline__ unsigned short f2bf(float x) {
  union { float f; unsigned u; } un; un.f = x;
  unsigned r = un.u + 0x7FFFu + ((un.u >> 16) & 1u);
  return (unsigned short)(r >> 16);
}

#define MROWS 50688   // 512 windows * 99 tokens
#define XTOK  50176   // 2*8*56*56 spatial tokens
#define GT_OFF 9633792
#define SCALE_Q 0.17677669529663687f

// ---------------- weight fp32 -> bf16 transposed ----------------
// layout: qkvwT[576][192] @0 | projwT[192][192] @110592 | fc1wT[768][192] @147456 | fc2wT[192][768] @294912
__global__ __launch_bounds__(256) void prep_w(
    const float* __restrict__ qkvw, const float* __restrict__ projw,
    const float* __restrict__ fc1w, const float* __restrict__ fc2w,
    unsigned short* __restrict__ out)
{
  int idx = blockIdx.x * 256 + threadIdx.x; // grid covers 442368 exactly
  float v;
  if (idx < 110592)      { int n = idx / 192, k = idx - n * 192; v = qkvw[k * 576 + n]; }
  else if (idx < 147456) { int j = idx - 110592; int n = j / 192, k = j - n * 192; v = projw[k * 192 + n]; }
  else if (idx < 294912) { int j = idx - 147456; int n = j / 192, k = j - n * 192; v = fc1w[k * 768 + n]; }
  else                   { int j = idx - 294912; int n = j / 768, k = j - n * 768; v = fc2w[k * 192 + n]; }
  out[idx] = f2bf(v);
}

// ---------------- LN1 + shift + window partition + global-token concat ----------------
__global__ __launch_bounds__(256) void ln1_kernel(
    const float* __restrict__ x, const float* __restrict__ gtok,
    const float* __restrict__ lw, const float* __restrict__ lb,
    unsigned short* __restrict__ out) // [50688][192] bf16
{
  int row = blockIdx.x * 4 + (threadIdx.x >> 6);
  int lane = threadIdx.x & 63;
  int win = row / 99, t = row - win * 99;
  size_t obase = (size_t)row * 192;
  if (t == 0) {
    const float* src = gtok + (size_t)win * 192;
    out[obase + lane]       = f2bf(src[lane]);
    out[obase + lane + 64]  = f2bf(src[lane + 64]);
    out[obase + lane + 128] = f2bf(src[lane + 128]);
    return;
  }
  int b = win >> 8, wi = win & 255;
  int wd = wi >> 6, wh = (wi >> 3) & 7, ww = wi & 7;
  int tt = t - 1, td = tt / 49, rr = tt - td * 49, th = rr / 7, tw = rr - th * 7;
  int d = (wd * 2 + td + 1) & 7;
  int h = wh * 7 + th + 3; if (h >= 56) h -= 56;
  int wc = ww * 7 + tw + 3; if (wc >= 56) wc -= 56;
  const float* src = x + ((size_t)(((b * 8 + d) * 56 + h) * 56 + wc)) * 192;
  float v0 = src[lane], v1 = src[lane + 64], v2 = src[lane + 128];
  float s = v0 + v1 + v2;
  float ss = v0 * v0 + v1 * v1 + v2 * v2;
  #pragma unroll
  for (int off = 32; off; off >>= 1) { s += __shfl_xor(s, off); ss += __shfl_xor(ss, off); }
  float mean = s * (1.0f / 192.0f);
  float var = ss * (1.0f / 192.0f) - mean * mean;
  float rstd = rsqrtf(var + 1e-5f);
  out[obase + lane]       = f2bf((v0 - mean) * rstd * lw[lane]       + lb[lane]);
  out[obase + lane + 64]  = f2bf((v1 - mean) * rstd * lw[lane + 64]  + lb[lane + 64]);
  out[obase + lane + 128] = f2bf((v2 - mean) * rstd * lw[lane + 128] + lb[lane + 128]);
}

// ---------------- LN2 (rows = x1 tokens then gt) ----------------
__global__ __launch_bounds__(256) void ln2_kernel(
    const float* __restrict__ resbuf,
    const float* __restrict__ lw, const float* __restrict__ lb,
    unsigned short* __restrict__ out)
{
  int row = blockIdx.x * 4 + (threadIdx.x >> 6);
  int lane = threadIdx.x & 63;
  const float* src = resbuf + (size_t)row * 192;
  float v0 = src[lane], v1 = src[lane + 64], v2 = src[lane + 128];
  float s = v0 + v1 + v2;
  float ss = v0 * v0 + v1 * v1 + v2 * v2;
  #pragma unroll
  for (int off = 32; off; off >>= 1) { s += __shfl_xor(s, off); ss += __shfl_xor(ss, off); }
  float mean = s * (1.0f / 192.0f);
  float var = ss * (1.0f / 192.0f) - mean * mean;
  float rstd = rsqrtf(var + 1e-5f);
  size_t obase = (size_t)row * 192;
  out[obase + lane]       = f2bf((v0 - mean) * rstd * lw[lane]       + lb[lane]);
  out[obase + lane + 64]  = f2bf((v1 - mean) * rstd * lw[lane + 64]  + lb[lane + 64]);
  out[obase + lane + 128] = f2bf((v2 - mean) * rstd * lw[lane + 128] + lb[lane + 128]);
}

// ---------------- GEMM: C[M x N] = A[M x K](bf16) @ BT[N x K]^T(bf16), tile 128x64, 4 waves ----------------
// MODE 0: qkv  (+bias, scale q block, store bf16, row-stride N=576)
// MODE 1: proj (+bias, scatter window-reverse + residual add into resbuf fp32)
// MODE 2: fc1  (+bias, exact GELU, store bf16)
// MODE 3: fc2  (+bias, + resbuf residual, store fp32 to d_out with x/gt split)
template<int MODE>
__global__ __launch_bounds__(256) void gemm_tpl(
    const unsigned short* __restrict__ A,
    const unsigned short* __restrict__ BT,
    const float* __restrict__ bias,
    unsigned short* __restrict__ outb,
    const float* __restrict__ xin,
    float* __restrict__ resbuf,
    float* __restrict__ dout,
    int N, int K)
{
  __shared__ unsigned short As[128][40];
  __shared__ unsigned short Bs[64][40];
  const int tid = threadIdx.x, lane = tid & 63, w = tid >> 6;
  const int wm = w >> 1, wn = w & 1;
  const int mbase = blockIdx.x * 128, nbase = blockIdx.y * 64;
  const int l15 = lane & 15, l4 = lane >> 4;

  f32x4 acc[4][2] = {};

  const int arow = tid >> 1, aseg = (tid & 1) * 16;
  const unsigned short* aptr = A + (size_t)(mbase + arow) * K + aseg;
  const int brow = tid >> 1;
  const unsigned short* bptr = BT + (size_t)(nbase + brow) * K + aseg;

  for (int kb = 0; kb < K; kb += 32) {
    int4 a0 = *reinterpret_cast<const int4*>(aptr + kb);
    int4 a1 = *reinterpret_cast<const int4*>(aptr + kb + 8);
    *reinterpret_cast<int4*>(&As[arow][aseg])     = a0;
    *reinterpret_cast<int4*>(&As[arow][aseg + 8]) = a1;
    if (tid < 128) {
      int4 b0 = *reinterpret_cast<const int4*>(bptr + kb);
      int4 b1 = *reinterpret_cast<const int4*>(bptr + kb + 8);
      *reinterpret_cast<int4*>(&Bs[brow][aseg])     = b0;
      *reinterpret_cast<int4*>(&Bs[brow][aseg + 8]) = b1;
    }
    __syncthreads();
    FragU af[4], bfr[2];
    #pragma unroll
    for (int mi = 0; mi < 4; mi++) {
      int r = wm * 64 + mi * 16 + l15;
      af[mi].h[0] = *reinterpret_cast<const bf16x4*>(&As[r][l4 * 4]);
      af[mi].h[1] = *reinterpret_cast<const bf16x4*>(&As[r][16 + l4 * 4]);
    }
    #pragma unroll
    for (int nj = 0; nj < 2; nj++) {
      int c = wn * 32 + nj * 16 + l15;
      bfr[nj].h[0] = *reinterpret_cast<const bf16x4*>(&Bs[c][l4 * 4]);
      bfr[nj].h[1] = *reinterpret_cast<const bf16x4*>(&Bs[c][16 + l4 * 4]);
    }
    #pragma unroll
    for (int mi = 0; mi < 4; mi++)
      #pragma unroll
      for (int nj = 0; nj < 2; nj++)
        acc[mi][nj] = __builtin_amdgcn_mfma_f32_16x16x32_bf16(af[mi].v, bfr[nj].v, acc[mi][nj], 0, 0, 0);
    __syncthreads();
  }

  #pragma unroll
  for (int mi = 0; mi < 4; mi++)
    #pragma unroll
    for (int nj = 0; nj < 2; nj++)
      #pragma unroll
      for (int reg = 0; reg < 4; reg++) {
        int r = mbase + wm * 64 + mi * 16 + l4 * 4 + reg;
        int c = nbase + wn * 32 + nj * 16 + l15;
        float v = acc[mi][nj][reg] + bias[c];
        if constexpr (MODE == 0) {
          if (c < 192) v *= SCALE_Q;
          outb[(size_t)r * N + c] = f2bf(v);
        } else if constexpr (MODE == 1) {
          int win = r / 99, t = r - win * 99;
          if (t == 0) {
            resbuf[(size_t)(XTOK + win) * 192 + c] = v;
          } else {
            int b = win >> 8, wi = win & 255;
            int wd = wi >> 6, wh = (wi >> 3) & 7, ww = wi & 7;
            int tt = t - 1, td = tt / 49, rr = tt - td * 49, th = rr / 7, tw = rr - th * 7;
            int d = (wd * 2 + td + 1) & 7;
            int h = wh * 7 + th + 3; if (h >= 56) h -= 56;
            int wc = ww * 7 + tw + 3; if (wc >= 56) wc -= 56;
            size_t idx = ((size_t)(((b * 8 + d) * 56 + h) * 56 + wc)) * 192 + c;
            resbuf[idx] = xin[idx] + v;
          }
        } else if constexpr (MODE == 2) {
          float g = 0.5f * v * (1.0f + erff(v * 0.70710678118654752f));
          outb[(size_t)r * N + c] = f2bf(g);
        } else {
          v += resbuf[(size_t)r * 192 + c];
          if (r < XTOK) dout[(size_t)r * 192 + c] = v;
          else dout[GT_OFF + (size_t)(r - XTOK) * 192 + c] = v;
        }
      }
}

// ---------------- attention per (window, head), N=99 padded to 128 ----------------
__global__ __launch_bounds__(256) void attn_kernel(
    const unsigned short* __restrict__ qkv, // [50688][576] bf16 (q pre-scaled)
    const float* __restrict__ rpb,          // [507][6]
    const float* __restrict__ amask,        // [256][98][98]
    unsigned short* __restrict__ out)       // [50688][192] bf16
{
  const int win = blockIdx.x / 6;
  const int head = blockIdx.x % 6;
  const int tid = threadIdx.x, lane = tid & 63, w = tid >> 6;
  const int l15 = lane & 15, l4 = lane >> 4;

  __shared__ unsigned short Qs[128][40];
  __shared__ unsigned short Ks[128][40];
  __shared__ unsigned short VTs[32][132];
  __shared__ unsigned short Ps[128][132];

  const size_t rowbase = (size_t)win * 99;

  // stage Q,K (rows >=99 zeroed)
  for (int idx = tid; idx < 512; idx += 256) {
    int r = idx >> 2, seg = (idx & 3) * 8;
    int4 zq = {0, 0, 0, 0}, zk = {0, 0, 0, 0};
    if (r < 99) {
      zq = *reinterpret_cast<const int4*>(qkv + (rowbase + r) * 576 + head * 32 + seg);
      zk = *reinterpret_cast<const int4*>(qkv + (rowbase + r) * 576 + 192 + head * 32 + seg);
    }
    *reinterpret_cast<int4*>(&Qs[r][seg]) = zq;
    *reinterpret_cast<int4*>(&Ks[r][seg]) = zk;
  }
  // stage V transposed
  for (int idx = tid; idx < 4096; idx += 256) {
    int t = idx >> 5, d = idx & 31;
    unsigned short v = 0;
    if (t < 99) v = qkv[(rowbase + t) * 576 + 384 + head * 32 + d];
    VTs[d][t] = v;
  }
  __syncthreads();

  // S = Q @ K^T : wave w owns rows [w*32, w*32+32)
  f32x4 acc[2][8] = {};
  {
    FragU a[2];
    #pragma unroll
    for (int mi = 0; mi < 2; mi++) {
      int r = w * 32 + mi * 16 + l15;
      a[mi].h[0] = *reinterpret_cast<const bf16x4*>(&Qs[r][l4 * 4]);
      a[mi].h[1] = *reinterpret_cast<const bf16x4*>(&Qs[r][16 + l4 * 4]);
    }
    #pragma unroll
    for (int nj = 0; nj < 8; nj++) {
      FragU b;
      int c = nj * 16 + l15;
      b.h[0] = *reinterpret_cast<const bf16x4*>(&Ks[c][l4 * 4]);
      b.h[1] = *reinterpret_cast<const bf16x4*>(&Ks[c][16 + l4 * 4]);
      acc[0][nj] = __builtin_amdgcn_mfma_f32_16x16x32_bf16(a[0].v, b.v, acc[0][nj], 0, 0, 0);
      acc[1][nj] = __builtin_amdgcn_mfma_f32_16x16x32_bf16(a[1].v, b.v, acc[1][nj], 0, 0, 0);
    }
  }

  // extras + softmax (row-wise; row lives across 8 in-reg cols x 16 lanes)
  const float* maskw = amask + (size_t)(win & 255) * 9604;
  #pragma unroll
  for (int mi = 0; mi < 2; mi++) {
    #pragma unroll
    for (int reg = 0; reg < 4; reg++) {
      int r = w * 32 + mi * 16 + l4 * 4 + reg;
      float vals[8];
      #pragma unroll
      for (int nj = 0; nj < 8; nj++) {
        float s = acc[mi][nj][reg];
        int c = nj * 16 + l15;
        if (c >= 99) s = -1e30f;
        else if (r >= 1 && r < 99 && c >= 1) {
          int ti = r - 1, tj = c - 1;
          int tdi = ti / 49, ri = ti - tdi * 49, thi = ri / 7, twi = ri - thi * 7;
          int tdj = tj / 49, rj = tj - tdj * 49, thj = rj / 7, twj = rj - thj * 7;
          int rel = (tdi - tdj + 1) * 169 + (thi - thj + 6) * 13 + (twi - twj + 6);
          s += rpb[rel * 6 + head] + maskw[ti * 98 + tj];
        }
        vals[nj] = s;
      }
      float m = vals[0];
      #pragma unroll
      for (int nj = 1; nj < 8; nj++) m = fmaxf(m, vals[nj]);
      #pragma unroll
      for (int off = 1; off < 16; off <<= 1) m = fmaxf(m, __shfl_xor(m, off));
      float sum = 0.0f;
      #pragma unroll
      for (int nj = 0; nj < 8; nj++) { vals[nj] = __expf(vals[nj] - m); sum += vals[nj]; }
      #pragma unroll
      for (int off = 1; off < 16; off <<= 1) sum += __shfl_xor(sum, off);
      float inv = 1.0f / sum;
      #pragma unroll
      for (int nj = 0; nj < 8; nj++) Ps[r][nj * 16 + l15] = f2bf(vals[nj] * inv);
    }
  }
  __syncthreads();

  // out = P @ V : wave w rows [w*32, +32), cols 32
  f32x4 oacc[2][2] = {};
  #pragma unroll
  for (int ks = 0; ks < 4; ks++) {
    FragU pa[2];
    #pragma unroll
    for (int mi = 0; mi < 2; mi++) {
      int r = w * 32 + mi * 16 + l15;
      pa[mi].h[0] = *reinterpret_cast<const bf16x4*>(&Ps[r][ks * 32 + l4 * 4]);
      pa[mi].h[1] = *reinterpret_cast<const bf16x4*>(&Ps[r][ks * 32 + 16 + l4 * 4]);
    }
    #pragma unroll
    for (int nj = 0; nj < 2; nj++) {
      FragU vb;
      int d = nj * 16 + l15;
      vb.h[0] = *reinterpret_cast<const bf16x4*>(&VTs[d][ks * 32 + l4 * 4]);
      vb.h[1] = *reinterpret_cast<const bf16x4*>(&VTs[d][ks * 32 + 16 + l4 * 4]);
      oacc[0][nj] = __builtin_amdgcn_mfma_f32_16x16x32_bf16(pa[0].v, vb.v, oacc[0][nj], 0, 0, 0);
      oacc[1][nj] = __builtin_amdgcn_mfma_f32_16x16x32_bf16(pa[1].v, vb.v, oacc[1][nj], 0, 0, 0);
    }
  }
  #pragma unroll
  for (int mi = 0; mi < 2; mi++)
    #pragma unroll
    for (int nj = 0; nj < 2; nj++)
      #pragma unroll
      for (int reg = 0; reg < 4; reg++) {
        int r = w * 32 + mi * 16 + l4 * 4 + reg;
        if (r < 99) out[(rowbase + r) * 192 + head * 32 + nj * 16 + l15] = f2bf(oacc[mi][nj][reg]);
      }
}

// ---------------- host ----------------
extern "C" void kernel_launch(void* const* d_in, const int* in_sizes, int n_in,
                              void* d_out, int out_size, void* d_ws, size_t ws_size,
                              hipStream_t stream) {
  (void)in_sizes; (void)n_in; (void)out_size; (void)ws_size;
  const float* x     = (const float*)d_in[0];
  const float* gtok  = (const float*)d_in[1];
  // d_in[2] = position (unused by reference)
  const float* amask = (const float*)d_in[3];
  const float* n1w   = (const float*)d_in[4];
  const float* n1b   = (const float*)d_in[5];
  const float* qkvw  = (const float*)d_in[6];
  const float* qkvb  = (const float*)d_in[7];
  const float* projw = (const float*)d_in[8];
  const float* projb = (const float*)d_in[9];
  const float* rpb   = (const float*)d_in[10];
  const float* n2w   = (const float*)d_in[11];
  const float* n2b   = (const float*)d_in[12];
  const float* fc1w  = (const float*)d_in[13];
  const float* fc1b  = (const float*)d_in[14];
  const float* fc2w  = (const float*)d_in[15];
  const float* fc2b  = (const float*)d_in[16];

  char* ws = (char*)d_ws;
  unsigned short* wbuf = (unsigned short*)ws;              // 442368 bf16 weights (transposed)
  unsigned short* X    = (unsigned short*)(ws + 884736);   // 50688x192 bf16 (xw -> attn_out -> ln2)
  unsigned short* Qb   = (unsigned short*)(ws + 20348928); // 50688x576 bf16 qkv, then 50688x768 bf16 h
  float*          Rb   = (float*)(ws + 98205696);          // 50688x192 fp32 (x1 tokens + gt rows)
  float* dout = (float*)d_out;

  prep_w<<<1728, 256, 0, stream>>>(qkvw, projw, fc1w, fc2w, wbuf);
  ln1_kernel<<<12672, 256, 0, stream>>>(x, gtok, n1w, n1b, X);
  gemm_tpl<0><<<dim3(396, 9), 256, 0, stream>>>(X, wbuf, qkvb, Qb, nullptr, nullptr, nullptr, 576, 192);
  attn_kernel<<<3072, 256, 0, stream>>>(Qb, rpb, amask, X);
  gemm_tpl<1><<<dim3(396, 3), 256, 0, stream>>>(X, wbuf + 110592, projb, nullptr, x, Rb, nullptr, 192, 192);
  ln2_kernel<<<12672, 256, 0, stream>>>(Rb, n2w, n2b, X);
  gemm_tpl<2><<<dim3(396, 12), 256, 0, stream>>>(X, wbuf + 147456, fc1b, Qb, nullptr, nullptr, nullptr, 768, 192);
  gemm_tpl<3><<<dim3(396, 3), 256, 0, stream>>>(Qb, wbuf + 294912, fc2b, nullptr, nullptr, Rb, dout, 192, 768);
}

// Round 2
// 348.693 us; speedup vs baseline: 1.1191x; 1.1191x over previous
//
#include <hip/hip_runtime.h>
#include <math.h>

// ---------------- types / helpers ----------------
typedef float f32x4 __attribute__((ext_vector_type(4)));
typedef __bf16 bf16x4 __attribute__((ext_vector_type(4)));
typedef __bf16 bf16x8 __attribute__((ext_vector_type(8)));

union FragU { bf16x8 v; bf16x4 h[2]; };

__device__ __forceinline__ unsigned short f2bf(float x) {
  union { float f; unsigned u; } un; un.f = x;
  unsigned r = un.u + 0x7FFFu + ((un.u >> 16) & 1u);
  return (unsigned short)(r >> 16);
}
__device__ __forceinline__ float bf2f(unsigned short h) {
  union { unsigned u; float f; } un; un.u = ((unsigned)h) << 16;
  return un.f;
}

#define MROWS 50688   // 512 windows * 99 tokens
#define XTOK  50176   // 2*8*56*56 spatial tokens
#define GT_OFF 9633792
#define SCALE_Q 0.17677669529663687f

// ---------------- weight fp32 -> bf16 transposed ----------------
// layout: qkvwT[576][192] @0 | projwT[192][192] @110592 | fc1wT[768][192] @147456 | fc2wT[192][768] @294912
__global__ __launch_bounds__(256) void prep_w(
    const float* __restrict__ qkvw, const float* __restrict__ projw,
    const float* __restrict__ fc1w, const float* __restrict__ fc2w,
    unsigned short* __restrict__ out)
{
  int idx = blockIdx.x * 256 + threadIdx.x; // grid covers 442368 exactly
  float v;
  if (idx < 110592)      { int n = idx / 192, k = idx - n * 192; v = qkvw[k * 576 + n]; }
  else if (idx < 147456) { int j = idx - 110592; int n = j / 192, k = j - n * 192; v = projw[k * 192 + n]; }
  else if (idx < 294912) { int j = idx - 147456; int n = j / 192, k = j - n * 192; v = fc1w[k * 768 + n]; }
  else                   { int j = idx - 294912; int n = j / 768, k = j - n * 768; v = fc2w[k * 192 + n]; }
  out[idx] = f2bf(v);
}

// ---------------- combined rel-pos-bias + mask table ----------------
// Et[(win&255)*6 + head][99][100] bf16; row 0 / col 0 (global token) = 0
__global__ __launch_bounds__(256) void prep_extra(
    const float* __restrict__ rpb, const float* __restrict__ amask,
    unsigned short* __restrict__ Et)
{
  int idx = blockIdx.x * 256 + threadIdx.x; // 59400 blocks * 256 = 1536*9900 exactly
  int pair = idx / 9900;
  int rem = idx - pair * 9900;
  int r = rem / 100, c = rem - r * 100;
  int head = pair % 6, w256 = pair / 6;
  float v = 0.0f;
  if (r >= 1 && c >= 1 && c <= 98) {
    int ti = r - 1, tj = c - 1;
    int tdi = ti / 49, ri = ti - tdi * 49, thi = ri / 7, twi = ri - thi * 7;
    int tdj = tj / 49, rj = tj - tdj * 49, thj = rj / 7, twj = rj - thj * 7;
    int rel = (tdi - tdj + 1) * 169 + (thi - thj + 6) * 13 + (twi - twj + 6);
    v = rpb[rel * 6 + head] + amask[(size_t)w256 * 9604 + ti * 98 + tj];
  }
  Et[idx] = f2bf(v);
}

// ---------------- LN1 + shift + window partition + global-token concat ----------------
__global__ __launch_bounds__(256) void ln1_kernel(
    const float* __restrict__ x, const float* __restrict__ gtok,
    const float* __restrict__ lw, const float* __restrict__ lb,
    unsigned short* __restrict__ out) // [50688][192] bf16
{
  int row = blockIdx.x * 4 + (threadIdx.x >> 6);
  int lane = threadIdx.x & 63;
  int win = row / 99, t = row - win * 99;
  size_t obase = (size_t)row * 192;
  if (t == 0) {
    const float* src = gtok + (size_t)win * 192;
    out[obase + lane]       = f2bf(src[lane]);
    out[obase + lane + 64]  = f2bf(src[lane + 64]);
    out[obase + lane + 128] = f2bf(src[lane + 128]);
    return;
  }
  int b = win >> 8, wi = win & 255;
  int wd = wi >> 6, wh = (wi >> 3) & 7, ww = wi & 7;
  int tt = t - 1, td = tt / 49, rr = tt - td * 49, th = rr / 7, tw = rr - th * 7;
  int d = (wd * 2 + td + 1) & 7;
  int h = wh * 7 + th + 3; if (h >= 56) h -= 56;
  int wc = ww * 7 + tw + 3; if (wc >= 56) wc -= 56;
  const float* src = x + ((size_t)(((b * 8 + d) * 56 + h) * 56 + wc)) * 192;
  float v0 = src[lane], v1 = src[lane + 64], v2 = src[lane + 128];
  float s = v0 + v1 + v2;
  float ss = v0 * v0 + v1 * v1 + v2 * v2;
  #pragma unroll
  for (int off = 32; off; off >>= 1) { s += __shfl_xor(s, off); ss += __shfl_xor(ss, off); }
  float mean = s * (1.0f / 192.0f);
  float var = ss * (1.0f / 192.0f) - mean * mean;
  float rstd = rsqrtf(var + 1e-5f);
  out[obase + lane]       = f2bf((v0 - mean) * rstd * lw[lane]       + lb[lane]);
  out[obase + lane + 64]  = f2bf((v1 - mean) * rstd * lw[lane + 64]  + lb[lane + 64]);
  out[obase + lane + 128] = f2bf((v2 - mean) * rstd * lw[lane + 128] + lb[lane + 128]);
}

// ---------------- LN2 (rows = x1 tokens then gt) ----------------
__global__ __launch_bounds__(256) void ln2_kernel(
    const float* __restrict__ resbuf,
    const float* __restrict__ lw, const float* __restrict__ lb,
    unsigned short* __restrict__ out)
{
  int row = blockIdx.x * 4 + (threadIdx.x >> 6);
  int lane = threadIdx.x & 63;
  const float* src = resbuf + (size_t)row * 192;
  float v0 = src[lane], v1 = src[lane + 64], v2 = src[lane + 128];
  float s = v0 + v1 + v2;
  float ss = v0 * v0 + v1 * v1 + v2 * v2;
  #pragma unroll
  for (int off = 32; off; off >>= 1) { s += __shfl_xor(s, off); ss += __shfl_xor(ss, off); }
  float mean = s * (1.0f / 192.0f);
  float var = ss * (1.0f / 192.0f) - mean * mean;
  float rstd = rsqrtf(var + 1e-5f);
  size_t obase = (size_t)row * 192;
  out[obase + lane]       = f2bf((v0 - mean) * rstd * lw[lane]       + lb[lane]);
  out[obase + lane + 64]  = f2bf((v1 - mean) * rstd * lw[lane + 64]  + lb[lane + 64]);
  out[obase + lane + 128] = f2bf((v2 - mean) * rstd * lw[lane + 128] + lb[lane + 128]);
}

// ---------------- GEMM: C[M x N] = A[M x K](bf16) @ BT[N x K]^T(bf16), tile 128x64, 4 waves ----------------
// MODE 0: qkv  (+bias, scale q block, store bf16, row-stride N=576)
// MODE 1: proj (+bias, scatter window-reverse + residual add into resbuf fp32)
// MODE 2: fc1  (+bias, exact GELU, store bf16)
// MODE 3: fc2  (+bias, + resbuf residual, store fp32 to d_out with x/gt split)
template<int MODE>
__global__ __launch_bounds__(256) void gemm_tpl(
    const unsigned short* __restrict__ A,
    const unsigned short* __restrict__ BT,
    const float* __restrict__ bias,
    unsigned short* __restrict__ outb,
    const float* __restrict__ xin,
    float* __restrict__ resbuf,
    float* __restrict__ dout,
    int N, int K)
{
  __shared__ unsigned short As[128][40];
  __shared__ unsigned short Bs[64][40];
  const int tid = threadIdx.x, lane = tid & 63, w = tid >> 6;
  const int wm = w >> 1, wn = w & 1;
  const int mbase = blockIdx.x * 128, nbase = blockIdx.y * 64;
  const int l15 = lane & 15, l4 = lane >> 4;

  f32x4 acc[4][2] = {};

  const int arow = tid >> 1, aseg = (tid & 1) * 16;
  const unsigned short* aptr = A + (size_t)(mbase + arow) * K + aseg;
  const int brow = tid >> 1;
  const unsigned short* bptr = BT + (size_t)(nbase + brow) * K + aseg;

  for (int kb = 0; kb < K; kb += 32) {
    int4 a0 = *reinterpret_cast<const int4*>(aptr + kb);
    int4 a1 = *reinterpret_cast<const int4*>(aptr + kb + 8);
    *reinterpret_cast<int4*>(&As[arow][aseg])     = a0;
    *reinterpret_cast<int4*>(&As[arow][aseg + 8]) = a1;
    if (tid < 128) {
      int4 b0 = *reinterpret_cast<const int4*>(bptr + kb);
      int4 b1 = *reinterpret_cast<const int4*>(bptr + kb + 8);
      *reinterpret_cast<int4*>(&Bs[brow][aseg])     = b0;
      *reinterpret_cast<int4*>(&Bs[brow][aseg + 8]) = b1;
    }
    __syncthreads();
    FragU af[4], bfr[2];
    #pragma unroll
    for (int mi = 0; mi < 4; mi++) {
      int r = wm * 64 + mi * 16 + l15;
      af[mi].h[0] = *reinterpret_cast<const bf16x4*>(&As[r][l4 * 4]);
      af[mi].h[1] = *reinterpret_cast<const bf16x4*>(&As[r][16 + l4 * 4]);
    }
    #pragma unroll
    for (int nj = 0; nj < 2; nj++) {
      int c = wn * 32 + nj * 16 + l15;
      bfr[nj].h[0] = *reinterpret_cast<const bf16x4*>(&Bs[c][l4 * 4]);
      bfr[nj].h[1] = *reinterpret_cast<const bf16x4*>(&Bs[c][16 + l4 * 4]);
    }
    #pragma unroll
    for (int mi = 0; mi < 4; mi++)
      #pragma unroll
      for (int nj = 0; nj < 2; nj++)
        acc[mi][nj] = __builtin_amdgcn_mfma_f32_16x16x32_bf16(af[mi].v, bfr[nj].v, acc[mi][nj], 0, 0, 0);
    __syncthreads();
  }

  #pragma unroll
  for (int mi = 0; mi < 4; mi++)
    #pragma unroll
    for (int nj = 0; nj < 2; nj++)
      #pragma unroll
      for (int reg = 0; reg < 4; reg++) {
        int r = mbase + wm * 64 + mi * 16 + l4 * 4 + reg;
        int c = nbase + wn * 32 + nj * 16 + l15;
        float v = acc[mi][nj][reg] + bias[c];
        if constexpr (MODE == 0) {
          if (c < 192) v *= SCALE_Q;
          outb[(size_t)r * N + c] = f2bf(v);
        } else if constexpr (MODE == 1) {
          int win = r / 99, t = r - win * 99;
          if (t == 0) {
            resbuf[(size_t)(XTOK + win) * 192 + c] = v;
          } else {
            int b = win >> 8, wi = win & 255;
            int wd = wi >> 6, wh = (wi >> 3) & 7, ww = wi & 7;
            int tt = t - 1, td = tt / 49, rr = tt - td * 49, th = rr / 7, tw = rr - th * 7;
            int d = (wd * 2 + td + 1) & 7;
            int h = wh * 7 + th + 3; if (h >= 56) h -= 56;
            int wc = ww * 7 + tw + 3; if (wc >= 56) wc -= 56;
            size_t idx = ((size_t)(((b * 8 + d) * 56 + h) * 56 + wc)) * 192 + c;
            resbuf[idx] = xin[idx] + v;
          }
        } else if constexpr (MODE == 2) {
          float g = 0.5f * v * (1.0f + erff(v * 0.70710678118654752f));
          outb[(size_t)r * N + c] = f2bf(g);
        } else {
          v += resbuf[(size_t)r * 192 + c];
          if (r < XTOK) dout[(size_t)r * 192 + c] = v;
          else dout[GT_OFF + (size_t)(r - XTOK) * 192 + c] = v;
        }
      }
}

// ---------------- attention per (window, head), N=99 padded to 128 ----------------
// LDS: SP region (33792 u16) holds Qs+Ks during QK^T, then Ps (wave-private rows).
__global__ __launch_bounds__(256) void attn_kernel(
    const unsigned short* __restrict__ qkv, // [50688][576] bf16 (q pre-scaled)
    const unsigned short* __restrict__ Et,  // [1536][99][100] bf16 combined extra
    unsigned short* __restrict__ out)       // [50688][192] bf16
{
  const int win = blockIdx.x / 6;
  const int head = blockIdx.x % 6;
  const int tid = threadIdx.x, lane = tid & 63, w = tid >> 6;
  const int l15 = lane & 15, l4 = lane >> 4;

  __shared__ __align__(16) unsigned short SP[128 * 132];
  __shared__ __align__(16) unsigned short VTs[32][132];
  unsigned short (*Qs)[40] = reinterpret_cast<unsigned short(*)[40]>(SP);
  unsigned short (*Ks)[40] = reinterpret_cast<unsigned short(*)[40]>(SP + 5120);
  unsigned short (*Ps)[132] = reinterpret_cast<unsigned short(*)[132]>(SP);

  const size_t rowbase = (size_t)win * 99;

  // stage Q,K (rows >=99 zeroed)
  for (int idx = tid; idx < 512; idx += 256) {
    int r = idx >> 2, seg = (idx & 3) * 8;
    int4 zq = {0, 0, 0, 0}, zk = {0, 0, 0, 0};
    if (r < 99) {
      zq = *reinterpret_cast<const int4*>(qkv + (rowbase + r) * 576 + head * 32 + seg);
      zk = *reinterpret_cast<const int4*>(qkv + (rowbase + r) * 576 + 192 + head * 32 + seg);
    }
    *reinterpret_cast<int4*>(&Qs[r][seg]) = zq;
    *reinterpret_cast<int4*>(&Ks[r][seg]) = zk;
  }
  // stage V transposed
  for (int idx = tid; idx < 4096; idx += 256) {
    int t = idx >> 5, d = idx & 31;
    unsigned short v = 0;
    if (t < 99) v = qkv[(rowbase + t) * 576 + 384 + head * 32 + d];
    VTs[d][t] = v;
  }
  __syncthreads();

  // S = Q @ K^T : wave w owns rows [w*32, w*32+32)
  f32x4 acc[2][8] = {};
  {
    FragU a[2];
    #pragma unroll
    for (int mi = 0; mi < 2; mi++) {
      int r = w * 32 + mi * 16 + l15;
      a[mi].h[0] = *reinterpret_cast<const bf16x4*>(&Qs[r][l4 * 4]);
      a[mi].h[1] = *reinterpret_cast<const bf16x4*>(&Qs[r][16 + l4 * 4]);
    }
    #pragma unroll
    for (int nj = 0; nj < 8; nj++) {
      FragU b;
      int c = nj * 16 + l15;
      b.h[0] = *reinterpret_cast<const bf16x4*>(&Ks[c][l4 * 4]);
      b.h[1] = *reinterpret_cast<const bf16x4*>(&Ks[c][16 + l4 * 4]);
      acc[0][nj] = __builtin_amdgcn_mfma_f32_16x16x32_bf16(a[0].v, b.v, acc[0][nj], 0, 0, 0);
      acc[1][nj] = __builtin_amdgcn_mfma_f32_16x16x32_bf16(a[1].v, b.v, acc[1][nj], 0, 0, 0);
    }
  }
  __syncthreads();  // all waves done reading Qs/Ks before Ps overwrites SP

  // extras + softmax (row-wise; row lives across 8 in-reg cols x 16 lanes)
  const unsigned short* etw = Et + ((size_t)((win & 255) * 6 + head)) * 9900;
  #pragma unroll
  for (int mi = 0; mi < 2; mi++) {
    #pragma unroll
    for (int reg = 0; reg < 4; reg++) {
      int r = w * 32 + mi * 16 + l4 * 4 + reg;
      float vals[8];
      #pragma unroll
      for (int nj = 0; nj < 8; nj++) {
        float s = acc[mi][nj][reg];
        int c = nj * 16 + l15;
        if (c >= 99) s = -1e30f;
        else if (r < 99) s += bf2f(etw[r * 100 + c]);
        vals[nj] = s;
      }
      float m = vals[0];
      #pragma unroll
      for (int nj = 1; nj < 8; nj++) m = fmaxf(m, vals[nj]);
      #pragma unroll
      for (int off = 1; off < 16; off <<= 1) m = fmaxf(m, __shfl_xor(m, off));
      float sum = 0.0f;
      #pragma unroll
      for (int nj = 0; nj < 8; nj++) { vals[nj] = __expf(vals[nj] - m); sum += vals[nj]; }
      #pragma unroll
      for (int off = 1; off < 16; off <<= 1) sum += __shfl_xor(sum, off);
      float inv = 1.0f / sum;
      #pragma unroll
      for (int nj = 0; nj < 8; nj++) Ps[r][nj * 16 + l15] = f2bf(vals[nj] * inv);
    }
  }
  // Ps rows are wave-private: no barrier needed before PV.

  // out = P @ V : wave w rows [w*32, +32), cols 32
  f32x4 oacc[2][2] = {};
  #pragma unroll
  for (int ks = 0; ks < 4; ks++) {
    FragU pa[2];
    #pragma unroll
    for (int mi = 0; mi < 2; mi++) {
      int r = w * 32 + mi * 16 + l15;
      pa[mi].h[0] = *reinterpret_cast<const bf16x4*>(&Ps[r][ks * 32 + l4 * 4]);
      pa[mi].h[1] = *reinterpret_cast<const bf16x4*>(&Ps[r][ks * 32 + 16 + l4 * 4]);
    }
    #pragma unroll
    for (int nj = 0; nj < 2; nj++) {
      FragU vb;
      int d = nj * 16 + l15;
      vb.h[0] = *reinterpret_cast<const bf16x4*>(&VTs[d][ks * 32 + l4 * 4]);
      vb.h[1] = *reinterpret_cast<const bf16x4*>(&VTs[d][ks * 32 + 16 + l4 * 4]);
      oacc[0][nj] = __builtin_amdgcn_mfma_f32_16x16x32_bf16(pa[0].v, vb.v, oacc[0][nj], 0, 0, 0);
      oacc[1][nj] = __builtin_amdgcn_mfma_f32_16x16x32_bf16(pa[1].v, vb.v, oacc[1][nj], 0, 0, 0);
    }
  }
  #pragma unroll
  for (int mi = 0; mi < 2; mi++)
    #pragma unroll
    for (int nj = 0; nj < 2; nj++)
      #pragma unroll
      for (int reg = 0; reg < 4; reg++) {
        int r = w * 32 + mi * 16 + l4 * 4 + reg;
        if (r < 99) out[(rowbase + r) * 192 + head * 32 + nj * 16 + l15] = f2bf(oacc[mi][nj][reg]);
      }
}

// ---------------- host ----------------
extern "C" void kernel_launch(void* const* d_in, const int* in_sizes, int n_in,
                              void* d_out, int out_size, void* d_ws, size_t ws_size,
                              hipStream_t stream) {
  (void)in_sizes; (void)n_in; (void)out_size; (void)ws_size;
  const float* x     = (const float*)d_in[0];
  const float* gtok  = (const float*)d_in[1];
  // d_in[2] = position (unused by reference)
  const float* amask = (const float*)d_in[3];
  const float* n1w   = (const float*)d_in[4];
  const float* n1b   = (const float*)d_in[5];
  const float* qkvw  = (const float*)d_in[6];
  const float* qkvb  = (const float*)d_in[7];
  const float* projw = (const float*)d_in[8];
  const float* projb = (const float*)d_in[9];
  const float* rpb   = (const float*)d_in[10];
  const float* n2w   = (const float*)d_in[11];
  const float* n2b   = (const float*)d_in[12];
  const float* fc1w  = (const float*)d_in[13];
  const float* fc1b  = (const float*)d_in[14];
  const float* fc2w  = (const float*)d_in[15];
  const float* fc2b  = (const float*)d_in[16];

  char* ws = (char*)d_ws;
  unsigned short* wbuf = (unsigned short*)ws;              // 442368 bf16 weights (transposed)
  unsigned short* X    = (unsigned short*)(ws + 884736);   // 50688x192 bf16 (xw -> attn_out -> ln2)
  unsigned short* Qb   = (unsigned short*)(ws + 20348928); // 50688x576 bf16 qkv, then 50688x768 bf16 h
  float*          Rb   = (float*)(ws + 98205696);          // 50688x192 fp32 (x1 tokens + gt rows)
  unsigned short* Et   = (unsigned short*)(ws + 98205696); // 1536x9900 bf16 — aliases Rb (Et dead before MODE1 writes Rb)
  float* dout = (float*)d_out;

  prep_w<<<1728, 256, 0, stream>>>(qkvw, projw, fc1w, fc2w, wbuf);
  prep_extra<<<59400, 256, 0, stream>>>(rpb, amask, Et);
  ln1_kernel<<<12672, 256, 0, stream>>>(x, gtok, n1w, n1b, X);
  gemm_tpl<0><<<dim3(396, 9), 256, 0, stream>>>(X, wbuf, qkvb, Qb, nullptr, nullptr, nullptr, 576, 192);
  attn_kernel<<<3072, 256, 0, stream>>>(Qb, Et, X);
  gemm_tpl<1><<<dim3(396, 3), 256, 0, stream>>>(X, wbuf + 110592, projb, nullptr, x, Rb, nullptr, 192, 192);
  ln2_kernel<<<12672, 256, 0, stream>>>(Rb, n2w, n2b, X);
  gemm_tpl<2><<<dim3(396, 12), 256, 0, stream>>>(X, wbuf + 147456, fc1b, Qb, nullptr, nullptr, nullptr, 768, 192);
  gemm_tpl<3><<<dim3(396, 3), 256, 0, stream>>>(Qb, wbuf + 294912, fc2b, nullptr, nullptr, Rb, dout, 192, 768);
}

// Round 3
// 305.274 us; speedup vs baseline: 1.2783x; 1.1422x over previous
//
#include <hip/hip_runtime.h>
#include <math.h>

// ---------------- types / helpers ----------------
typedef float f32x4 __attribute__((ext_vector_type(4)));
typedef __bf16 bf16x4 __attribute__((ext_vector_type(4)));
typedef __bf16 bf16x8 __attribute__((ext_vector_type(8)));

union FragU { bf16x8 v; bf16x4 h[2]; };

__device__ __forceinline__ unsigned short f2bf(float x) {
  union { float f; unsigned u; } un; un.f = x;
  unsigned r = un.u + 0x7FFFu + ((un.u >> 16) & 1u);
  return (unsigned short)(r >> 16);
}
__device__ __forceinline__ float bf2f(unsigned short h) {
  union { unsigned u; float f; } un; un.u = ((unsigned)h) << 16;
  return un.f;
}

#define MROWS 50688   // 512 windows * 99 tokens
#define XTOK  50176   // 2*8*56*56 spatial tokens
#define GT_OFF 9633792
#define SCALE_Q 0.17677669529663687f

// ---------------- weight fp32 -> bf16 transposed ----------------
// layout: qkvwT[576][192] @0 | projwT[192][192] @110592 | fc1wT[768][192] @147456 | fc2wT[192][768] @294912
__global__ __launch_bounds__(256) void prep_w(
    const float* __restrict__ qkvw, const float* __restrict__ projw,
    const float* __restrict__ fc1w, const float* __restrict__ fc2w,
    unsigned short* __restrict__ out)
{
  int idx = blockIdx.x * 256 + threadIdx.x; // grid covers 442368 exactly
  float v;
  if (idx < 110592)      { int n = idx / 192, k = idx - n * 192; v = qkvw[k * 576 + n]; }
  else if (idx < 147456) { int j = idx - 110592; int n = j / 192, k = j - n * 192; v = projw[k * 192 + n]; }
  else if (idx < 294912) { int j = idx - 147456; int n = j / 192, k = j - n * 192; v = fc1w[k * 768 + n]; }
  else                   { int j = idx - 294912; int n = j / 768, k = j - n * 768; v = fc2w[k * 192 + n]; }
  out[idx] = f2bf(v);
}

// ---------------- packed transposed rel-pos-bias + mask table ----------------
// EtP[pair][base 16][t 4][r 99] u32 where pair = (win&255)*6+head.
// u32 = bf16(Et[r][c0]) | bf16(Et[r][c0+16])<<16, c0 = base + 32*t.
// (Et[r][c]: r = padded-S q row, c = padded-S k col; zero outside 1..98)
__global__ __launch_bounds__(256) void prep_extra(
    const float* __restrict__ rpb, const float* __restrict__ amask,
    unsigned int* __restrict__ EtP)
{
  int idx = blockIdx.x * 256 + threadIdx.x; // 38016 * 256 = 1536*6336 exactly
  int pair = idx / 6336;
  int rem = idx - pair * 6336;
  int base = rem / 396;
  int rem2 = rem - base * 396;
  int t = rem2 / 99;
  int r = rem2 - t * 99;
  int head = pair % 6, w256 = pair / 6;
  int c0 = base + 32 * t;
  unsigned int res = 0;
  #pragma unroll
  for (int h = 0; h < 2; h++) {
    int c = c0 + 16 * h;
    float v = 0.0f;
    if (r >= 1 && r <= 98 && c >= 1 && c <= 98) {
      int ti = r - 1, tj = c - 1;
      int tdi = ti / 49, ri = ti - tdi * 49, thi = ri / 7, twi = ri - thi * 7;
      int tdj = tj / 49, rj = tj - tdj * 49, thj = rj / 7, twj = rj - thj * 7;
      int rel = (tdi - tdj + 1) * 169 + (thi - thj + 6) * 13 + (twi - twj + 6);
      v = rpb[rel * 6 + head] + amask[(size_t)w256 * 9604 + ti * 98 + tj];
    }
    res |= ((unsigned int)f2bf(v)) << (16 * h);
  }
  EtP[idx] = res;
}

// ---------------- LN1 + shift + window partition + global-token concat ----------------
__global__ __launch_bounds__(256) void ln1_kernel(
    const float* __restrict__ x, const float* __restrict__ gtok,
    const float* __restrict__ lw, const float* __restrict__ lb,
    unsigned short* __restrict__ out) // [50688][192] bf16
{
  int row = blockIdx.x * 4 + (threadIdx.x >> 6);
  int lane = threadIdx.x & 63;
  int win = row / 99, t = row - win * 99;
  size_t obase = (size_t)row * 192;
  if (t == 0) {
    const float* src = gtok + (size_t)win * 192;
    out[obase + lane]       = f2bf(src[lane]);
    out[obase + lane + 64]  = f2bf(src[lane + 64]);
    out[obase + lane + 128] = f2bf(src[lane + 128]);
    return;
  }
  int b = win >> 8, wi = win & 255;
  int wd = wi >> 6, wh = (wi >> 3) & 7, ww = wi & 7;
  int tt = t - 1, td = tt / 49, rr = tt - td * 49, th = rr / 7, tw = rr - th * 7;
  int d = (wd * 2 + td + 1) & 7;
  int h = wh * 7 + th + 3; if (h >= 56) h -= 56;
  int wc = ww * 7 + tw + 3; if (wc >= 56) wc -= 56;
  const float* src = x + ((size_t)(((b * 8 + d) * 56 + h) * 56 + wc)) * 192;
  float v0 = src[lane], v1 = src[lane + 64], v2 = src[lane + 128];
  float s = v0 + v1 + v2;
  float ss = v0 * v0 + v1 * v1 + v2 * v2;
  #pragma unroll
  for (int off = 32; off; off >>= 1) { s += __shfl_xor(s, off); ss += __shfl_xor(ss, off); }
  float mean = s * (1.0f / 192.0f);
  float var = ss * (1.0f / 192.0f) - mean * mean;
  float rstd = rsqrtf(var + 1e-5f);
  out[obase + lane]       = f2bf((v0 - mean) * rstd * lw[lane]       + lb[lane]);
  out[obase + lane + 64]  = f2bf((v1 - mean) * rstd * lw[lane + 64]  + lb[lane + 64]);
  out[obase + lane + 128] = f2bf((v2 - mean) * rstd * lw[lane + 128] + lb[lane + 128]);
}

// ---------------- LN2 (rows = x1 tokens then gt) ----------------
__global__ __launch_bounds__(256) void ln2_kernel(
    const float* __restrict__ resbuf,
    const float* __restrict__ lw, const float* __restrict__ lb,
    unsigned short* __restrict__ out)
{
  int row = blockIdx.x * 4 + (threadIdx.x >> 6);
  int lane = threadIdx.x & 63;
  const float* src = resbuf + (size_t)row * 192;
  float v0 = src[lane], v1 = src[lane + 64], v2 = src[lane + 128];
  float s = v0 + v1 + v2;
  float ss = v0 * v0 + v1 * v1 + v2 * v2;
  #pragma unroll
  for (int off = 32; off; off >>= 1) { s += __shfl_xor(s, off); ss += __shfl_xor(ss, off); }
  float mean = s * (1.0f / 192.0f);
  float var = ss * (1.0f / 192.0f) - mean * mean;
  float rstd = rsqrtf(var + 1e-5f);
  size_t obase = (size_t)row * 192;
  out[obase + lane]       = f2bf((v0 - mean) * rstd * lw[lane]       + lb[lane]);
  out[obase + lane + 64]  = f2bf((v1 - mean) * rstd * lw[lane + 64]  + lb[lane + 64]);
  out[obase + lane + 128] = f2bf((v2 - mean) * rstd * lw[lane + 128] + lb[lane + 128]);
}

// ---------------- GEMM: C[M x N] = A[M x K](bf16) @ BT[N x K]^T(bf16), tile 128x64, 4 waves ----------------
template<int MODE>
__global__ __launch_bounds__(256) void gemm_tpl(
    const unsigned short* __restrict__ A,
    const unsigned short* __restrict__ BT,
    const float* __restrict__ bias,
    unsigned short* __restrict__ outb,
    const float* __restrict__ xin,
    float* __restrict__ resbuf,
    float* __restrict__ dout,
    int N, int K)
{
  __shared__ unsigned short As[128][40];
  __shared__ unsigned short Bs[64][40];
  const int tid = threadIdx.x, lane = tid & 63, w = tid >> 6;
  const int wm = w >> 1, wn = w & 1;
  const int mbase = blockIdx.x * 128, nbase = blockIdx.y * 64;
  const int l15 = lane & 15, l4 = lane >> 4;

  f32x4 acc[4][2] = {};

  const int arow = tid >> 1, aseg = (tid & 1) * 16;
  const unsigned short* aptr = A + (size_t)(mbase + arow) * K + aseg;
  const int brow = tid >> 1;
  const unsigned short* bptr = BT + (size_t)(nbase + brow) * K + aseg;

  for (int kb = 0; kb < K; kb += 32) {
    int4 a0 = *reinterpret_cast<const int4*>(aptr + kb);
    int4 a1 = *reinterpret_cast<const int4*>(aptr + kb + 8);
    *reinterpret_cast<int4*>(&As[arow][aseg])     = a0;
    *reinterpret_cast<int4*>(&As[arow][aseg + 8]) = a1;
    if (tid < 128) {
      int4 b0 = *reinterpret_cast<const int4*>(bptr + kb);
      int4 b1 = *reinterpret_cast<const int4*>(bptr + kb + 8);
      *reinterpret_cast<int4*>(&Bs[brow][aseg])     = b0;
      *reinterpret_cast<int4*>(&Bs[brow][aseg + 8]) = b1;
    }
    __syncthreads();
    FragU af[4], bfr[2];
    #pragma unroll
    for (int mi = 0; mi < 4; mi++) {
      int r = wm * 64 + mi * 16 + l15;
      af[mi].h[0] = *reinterpret_cast<const bf16x4*>(&As[r][l4 * 4]);
      af[mi].h[1] = *reinterpret_cast<const bf16x4*>(&As[r][16 + l4 * 4]);
    }
    #pragma unroll
    for (int nj = 0; nj < 2; nj++) {
      int c = wn * 32 + nj * 16 + l15;
      bfr[nj].h[0] = *reinterpret_cast<const bf16x4*>(&Bs[c][l4 * 4]);
      bfr[nj].h[1] = *reinterpret_cast<const bf16x4*>(&Bs[c][16 + l4 * 4]);
    }
    #pragma unroll
    for (int mi = 0; mi < 4; mi++)
      #pragma unroll
      for (int nj = 0; nj < 2; nj++)
        acc[mi][nj] = __builtin_amdgcn_mfma_f32_16x16x32_bf16(af[mi].v, bfr[nj].v, acc[mi][nj], 0, 0, 0);
    __syncthreads();
  }

  #pragma unroll
  for (int mi = 0; mi < 4; mi++)
    #pragma unroll
    for (int nj = 0; nj < 2; nj++)
      #pragma unroll
      for (int reg = 0; reg < 4; reg++) {
        int r = mbase + wm * 64 + mi * 16 + l4 * 4 + reg;
        int c = nbase + wn * 32 + nj * 16 + l15;
        float v = acc[mi][nj][reg] + bias[c];
        if constexpr (MODE == 0) {
          if (c < 192) v *= SCALE_Q;
          outb[(size_t)r * N + c] = f2bf(v);
        } else if constexpr (MODE == 1) {
          int win = r / 99, t = r - win * 99;
          if (t == 0) {
            resbuf[(size_t)(XTOK + win) * 192 + c] = v;
          } else {
            int b = win >> 8, wi = win & 255;
            int wd = wi >> 6, wh = (wi >> 3) & 7, ww = wi & 7;
            int tt = t - 1, td = tt / 49, rr = tt - td * 49, th = rr / 7, tw = rr - th * 7;
            int d = (wd * 2 + td + 1) & 7;
            int h = wh * 7 + th + 3; if (h >= 56) h -= 56;
            int wc = ww * 7 + tw + 3; if (wc >= 56) wc -= 56;
            size_t idx = ((size_t)(((b * 8 + d) * 56 + h) * 56 + wc)) * 192 + c;
            resbuf[idx] = xin[idx] + v;
          }
        } else if constexpr (MODE == 2) {
          float g = 0.5f * v * (1.0f + erff(v * 0.70710678118654752f));
          outb[(size_t)r * N + c] = f2bf(g);
        } else {
          v += resbuf[(size_t)r * 192 + c];
          if (r < XTOK) dout[(size_t)r * 192 + c] = v;
          else dout[GT_OFF + (size_t)(r - XTOK) * 192 + c] = v;
        }
      }
}

// ---------------- attention, swapped-operand (S^T = K@Q^T), P fully in-register ----------------
// grid: blockIdx.x = head*512 + win  (same-win heads 512 apart -> same XCD -> qkv L2 reuse)
__global__ __launch_bounds__(256, 4) void attn_kernel(
    const unsigned short* __restrict__ qkv, // [50688][576] bf16 (q pre-scaled)
    const unsigned int* __restrict__ EtP,   // packed extra table
    unsigned short* __restrict__ out)       // [50688][192] bf16
{
  const int win = blockIdx.x & 511;
  const int head = blockIdx.x >> 9;
  const int tid = threadIdx.x, lane = tid & 63, w = tid >> 6;
  const int l15 = lane & 15, l4 = (lane >> 4) & 3;

  __shared__ __align__(16) unsigned short Qs[128][40];
  __shared__ __align__(16) unsigned short Ks[128][40];
  __shared__ __align__(16) unsigned short VTs[32][136];

  const size_t rowbase = (size_t)win * 99;

  // ---- Et register preload (issued before staging; consumed after QK^T) ----
  const unsigned int* etb = EtP + (size_t)((win & 255) * 6 + head) * 6336;
  const int q0 = w * 16 + l15;            // < 64, always valid
  const int q1 = 64 + q0;
  const int r1 = q1 < 99 ? q1 : 0;        // clamp padding rows
  unsigned int et0[4][4], et1[4][4];
  #pragma unroll
  for (int reg = 0; reg < 4; reg++)
    #pragma unroll
    for (int t = 0; t < 4; t++) {
      int boff = ((l4 * 4 + reg) * 4 + t) * 99;
      et0[reg][t] = etb[boff + q0];
      et1[reg][t] = etb[boff + r1];
    }

  // ---- stage Q, K (row-major) and V (transposed), coalesced global reads ----
  for (int idx = tid; idx < 512; idx += 256) {
    int r = idx >> 2, seg = (idx & 3) * 8;
    int4 zq = {0,0,0,0}, zk = {0,0,0,0}, zv = {0,0,0,0};
    if (r < 99) {
      const unsigned short* src = qkv + (rowbase + r) * 576 + head * 32 + seg;
      zq = *reinterpret_cast<const int4*>(src);
      zk = *reinterpret_cast<const int4*>(src + 192);
      zv = *reinterpret_cast<const int4*>(src + 384);
    }
    *reinterpret_cast<int4*>(&Qs[r][seg]) = zq;
    *reinterpret_cast<int4*>(&Ks[r][seg]) = zk;
    const unsigned short* pv = reinterpret_cast<const unsigned short*>(&zv);
    #pragma unroll
    for (int j = 0; j < 8; j++) VTs[seg + j][r] = pv[j];
  }
  __syncthreads();

  f32x4 oacc[2][2] = {};

  #pragma unroll
  for (int qi = 0; qi < 2; qi++) {
    const int qrow = qi * 64 + w * 16 + l15;
    FragU qf;
    qf.h[0] = *reinterpret_cast<const bf16x4*>(&Qs[qrow][l4 * 4]);
    qf.h[1] = *reinterpret_cast<const bf16x4*>(&Qs[qrow][16 + l4 * 4]);

    // S^T tiles: nj = k-token tile (k = nj*16 + l4*4 + reg); tile 7 (k>=112) always masked -> skipped
    f32x4 sacc[7] = {};
    #pragma unroll
    for (int nj = 0; nj < 7; nj++) {
      FragU kf;
      kf.h[0] = *reinterpret_cast<const bf16x4*>(&Ks[nj * 16 + l15][l4 * 4]);
      kf.h[1] = *reinterpret_cast<const bf16x4*>(&Ks[nj * 16 + l15][16 + l4 * 4]);
      sacc[nj] = __builtin_amdgcn_mfma_f32_16x16x32_bf16(kf.v, qf.v, sacc[nj], 0, 0, 0);
    }

    // ---- softmax fully in-register (row q = l15; k spread over l4 x reg x nj) ----
    float m = -1e30f;
    #pragma unroll
    for (int nj = 0; nj < 7; nj++) {
      int t = nj >> 1;
      #pragma unroll
      for (int reg = 0; reg < 4; reg++) {
        unsigned int eu = qi ? et1[reg][t] : et0[reg][t];
        unsigned int bits = (nj & 1) ? (eu & 0xFFFF0000u) : (eu << 16);
        float s = sacc[nj][reg] + __uint_as_float(bits);
        if (nj == 6 && (96 + l4 * 4 + reg) >= 99) s = -1e30f;
        sacc[nj][reg] = s;
        m = fmaxf(m, s);
      }
    }
    m = fmaxf(m, __shfl_xor(m, 16));
    m = fmaxf(m, __shfl_xor(m, 32));
    float sum = 0.0f;
    #pragma unroll
    for (int nj = 0; nj < 7; nj++)
      #pragma unroll
      for (int reg = 0; reg < 4; reg++) {
        float e = __expf(sacc[nj][reg] - m);
        sacc[nj][reg] = e;
        sum += e;
      }
    sum += __shfl_xor(sum, 16);
    sum += __shfl_xor(sum, 32);
    const float inv = 1.0f / sum;

    // ---- PV: S^T acc layout == A-fragment layout, build pa in-lane ----
    #pragma unroll
    for (int ks = 0; ks < 4; ks++) {
      union { unsigned short u[8]; bf16x8 v; } pa;
      #pragma unroll
      for (int j = 0; j < 4; j++) {
        pa.u[j] = f2bf(sacc[2 * ks][j] * inv);
        pa.u[4 + j] = (ks == 3) ? (unsigned short)0 : f2bf(sacc[2 * ks + 1][j] * inv);
      }
      #pragma unroll
      for (int njd = 0; njd < 2; njd++) {
        FragU vb;
        vb.h[0] = *reinterpret_cast<const bf16x4*>(&VTs[njd * 16 + l15][ks * 32 + l4 * 4]);
        vb.h[1] = *reinterpret_cast<const bf16x4*>(&VTs[njd * 16 + l15][ks * 32 + 16 + l4 * 4]);
        oacc[qi][njd] = __builtin_amdgcn_mfma_f32_16x16x32_bf16(pa.v, vb.v, oacc[qi][njd], 0, 0, 0);
      }
    }
  }

  // ---- store: PV D layout col=l15=d, row=l4*4+reg=q-within-16 ----
  #pragma unroll
  for (int qi = 0; qi < 2; qi++)
    #pragma unroll
    for (int njd = 0; njd < 2; njd++)
      #pragma unroll
      for (int reg = 0; reg < 4; reg++) {
        int q = qi * 64 + w * 16 + l4 * 4 + reg;
        if (q < 99)
          out[(rowbase + q) * 192 + head * 32 + njd * 16 + l15] = f2bf(oacc[qi][njd][reg]);
      }
}

// ---------------- host ----------------
extern "C" void kernel_launch(void* const* d_in, const int* in_sizes, int n_in,
                              void* d_out, int out_size, void* d_ws, size_t ws_size,
                              hipStream_t stream) {
  (void)in_sizes; (void)n_in; (void)out_size; (void)ws_size;
  const float* x     = (const float*)d_in[0];
  const float* gtok  = (const float*)d_in[1];
  // d_in[2] = position (unused by reference)
  const float* amask = (const float*)d_in[3];
  const float* n1w   = (const float*)d_in[4];
  const float* n1b   = (const float*)d_in[5];
  const float* qkvw  = (const float*)d_in[6];
  const float* qkvb  = (const float*)d_in[7];
  const float* projw = (const float*)d_in[8];
  const float* projb = (const float*)d_in[9];
  const float* rpb   = (const float*)d_in[10];
  const float* n2w   = (const float*)d_in[11];
  const float* n2b   = (const float*)d_in[12];
  const float* fc1w  = (const float*)d_in[13];
  const float* fc1b  = (const float*)d_in[14];
  const float* fc2w  = (const float*)d_in[15];
  const float* fc2b  = (const float*)d_in[16];

  char* ws = (char*)d_ws;
  unsigned short* wbuf = (unsigned short*)ws;              // 442368 bf16 weights (transposed)
  unsigned short* X    = (unsigned short*)(ws + 884736);   // 50688x192 bf16 (xw -> attn_out -> ln2)
  unsigned short* Qb   = (unsigned short*)(ws + 20348928); // 50688x576 bf16 qkv, then 50688x768 bf16 h
  float*          Rb   = (float*)(ws + 98205696);          // 50688x192 fp32 (x1 tokens + gt rows)
  unsigned int*   EtP  = (unsigned int*)(ws + 98205696);   // 1536x6336 u32 — aliases Rb (dead before MODE1)
  float* dout = (float*)d_out;

  prep_w<<<1728, 256, 0, stream>>>(qkvw, projw, fc1w, fc2w, wbuf);
  prep_extra<<<38016, 256, 0, stream>>>(rpb, amask, EtP);
  ln1_kernel<<<12672, 256, 0, stream>>>(x, gtok, n1w, n1b, X);
  gemm_tpl<0><<<dim3(396, 9), 256, 0, stream>>>(X, wbuf, qkvb, Qb, nullptr, nullptr, nullptr, 576, 192);
  attn_kernel<<<3072, 256, 0, stream>>>(Qb, EtP, X);
  gemm_tpl<1><<<dim3(396, 3), 256, 0, stream>>>(X, wbuf + 110592, projb, nullptr, x, Rb, nullptr, 192, 192);
  ln2_kernel<<<12672, 256, 0, stream>>>(Rb, n2w, n2b, X);
  gemm_tpl<2><<<dim3(396, 12), 256, 0, stream>>>(X, wbuf + 147456, fc1b, Qb, nullptr, nullptr, nullptr, 768, 192);
  gemm_tpl<3><<<dim3(396, 3), 256, 0, stream>>>(Qb, wbuf + 294912, fc2b, nullptr, nullptr, Rb, dout, 192, 768);
}

// Round 4
// 249.092 us; speedup vs baseline: 1.5666x; 1.2255x over previous
//
#include <hip/hip_runtime.h>
#include <math.h>

// ---------------- types / helpers ----------------
typedef float f32x4 __attribute__((ext_vector_type(4)));
typedef __bf16 bf16x4 __attribute__((ext_vector_type(4)));
typedef __bf16 bf16x8 __attribute__((ext_vector_type(8)));

union FragU { bf16x8 v; bf16x4 h[2]; };

__device__ __forceinline__ unsigned short f2bf(float x) {
  union { float f; unsigned u; } un; un.f = x;
  unsigned r = un.u + 0x7FFFu + ((un.u >> 16) & 1u);
  return (unsigned short)(r >> 16);
}
__device__ __forceinline__ float bf2f(unsigned short h) {
  union { unsigned u; float f; } un; un.u = ((unsigned)h) << 16;
  return un.f;
}

#define MROWS 50688   // 512 windows * 99 tokens
#define XTOK  50176   // 2*8*56*56 spatial tokens
#define GT_OFF 9633792
#define SCALE_Q 0.17677669529663687f

// ---------------- weight fp32 -> bf16 transposed ----------------
// layout: qkvwT[576][192] @0 | projwT[192][192] @110592 | fc1wT[768][192] @147456 | fc2wT[192][768] @294912
__global__ __launch_bounds__(256) void prep_w(
    const float* __restrict__ qkvw, const float* __restrict__ projw,
    const float* __restrict__ fc1w, const float* __restrict__ fc2w,
    unsigned short* __restrict__ out)
{
  int idx = blockIdx.x * 256 + threadIdx.x; // grid covers 442368 exactly
  float v;
  if (idx < 110592)      { int n = idx / 192, k = idx - n * 192; v = qkvw[k * 576 + n]; }
  else if (idx < 147456) { int j = idx - 110592; int n = j / 192, k = j - n * 192; v = projw[k * 192 + n]; }
  else if (idx < 294912) { int j = idx - 147456; int n = j / 192, k = j - n * 192; v = fc1w[k * 768 + n]; }
  else                   { int j = idx - 294912; int n = j / 768, k = j - n * 768; v = fc2w[k * 192 + n]; }
  out[idx] = f2bf(v);
}

// ---------------- transposed packed mask table ----------------
// maskP[w256][base 16][t 4][r 99] u32 = bf16(mask-part at (r, c0)) | bf16(... c0+16)<<16,
// c0 = base + 32*t; zero outside r,c in 1..98. One block per w256; LDS transpose.
__global__ __launch_bounds__(256) void prep_maskT(
    const float* __restrict__ amask, unsigned int* __restrict__ maskP)
{
  __shared__ float M[98][99];            // pad to 99: stride 99 % 32 == 3 -> conflict-free
  const int tid = threadIdx.x, w256 = blockIdx.x;
  const float* src = amask + (size_t)w256 * 9604;
  for (int i = tid; i < 9604; i += 256) {
    int ti = i / 98, tj = i - ti * 98;
    M[ti][tj] = src[i];
  }
  __syncthreads();
  unsigned int* dst = maskP + (size_t)w256 * 6336;
  for (int o = tid; o < 6336; o += 256) {
    int base = o / 396, rem = o - base * 396;
    int t = rem / 99, r = rem - t * 99;
    int c0 = base + 32 * t;
    unsigned int res = 0;
    #pragma unroll
    for (int h = 0; h < 2; h++) {
      int c = c0 + 16 * h;
      float v = 0.0f;
      if (r >= 1 && c >= 1 && c <= 98) v = M[r - 1][c - 1];
      res |= ((unsigned int)f2bf(v)) << (16 * h);
    }
    dst[o] = res;
  }
}

// ---------------- transposed packed rel-pos-bias table ----------------
// rpbP[head][base 16][t 4][r 99] u32, same packing as maskP.
__global__ __launch_bounds__(256) void prep_rpbT(
    const float* __restrict__ rpb, unsigned int* __restrict__ rpbP)
{
  int idx = blockIdx.x * 256 + threadIdx.x;
  if (idx >= 38016) return;              // 6 * 6336
  int head = idx / 6336, o = idx - head * 6336;
  int base = o / 396, rem = o - base * 396;
  int t = rem / 99, r = rem - t * 99;
  int c0 = base + 32 * t;
  unsigned int res = 0;
  #pragma unroll
  for (int h = 0; h < 2; h++) {
    int c = c0 + 16 * h;
    float v = 0.0f;
    if (r >= 1 && c >= 1 && c <= 98) {
      int ti = r - 1, tj = c - 1;
      int tdi = ti / 49, ri = ti - tdi * 49, thi = ri / 7, twi = ri - thi * 7;
      int tdj = tj / 49, rj = tj - tdj * 49, thj = rj / 7, twj = rj - thj * 7;
      int rel = (tdi - tdj + 1) * 169 + (thi - thj + 6) * 13 + (twi - twj + 6);
      v = rpb[rel * 6 + head];
    }
    res |= ((unsigned int)f2bf(v)) << (16 * h);
  }
  rpbP[idx] = res;
}

// ---------------- LN1 + shift + window partition + global-token concat ----------------
__global__ __launch_bounds__(256) void ln1_kernel(
    const float* __restrict__ x, const float* __restrict__ gtok,
    const float* __restrict__ lw, const float* __restrict__ lb,
    unsigned short* __restrict__ out) // [50688][192] bf16
{
  int row = blockIdx.x * 4 + (threadIdx.x >> 6);
  int lane = threadIdx.x & 63;
  int win = row / 99, t = row - win * 99;
  size_t obase = (size_t)row * 192;
  if (t == 0) {
    const float* src = gtok + (size_t)win * 192;
    out[obase + lane]       = f2bf(src[lane]);
    out[obase + lane + 64]  = f2bf(src[lane + 64]);
    out[obase + lane + 128] = f2bf(src[lane + 128]);
    return;
  }
  int b = win >> 8, wi = win & 255;
  int wd = wi >> 6, wh = (wi >> 3) & 7, ww = wi & 7;
  int tt = t - 1, td = tt / 49, rr = tt - td * 49, th = rr / 7, tw = rr - th * 7;
  int d = (wd * 2 + td + 1) & 7;
  int h = wh * 7 + th + 3; if (h >= 56) h -= 56;
  int wc = ww * 7 + tw + 3; if (wc >= 56) wc -= 56;
  const float* src = x + ((size_t)(((b * 8 + d) * 56 + h) * 56 + wc)) * 192;
  float v0 = src[lane], v1 = src[lane + 64], v2 = src[lane + 128];
  float s = v0 + v1 + v2;
  float ss = v0 * v0 + v1 * v1 + v2 * v2;
  #pragma unroll
  for (int off = 32; off; off >>= 1) { s += __shfl_xor(s, off); ss += __shfl_xor(ss, off); }
  float mean = s * (1.0f / 192.0f);
  float var = ss * (1.0f / 192.0f) - mean * mean;
  float rstd = rsqrtf(var + 1e-5f);
  out[obase + lane]       = f2bf((v0 - mean) * rstd * lw[lane]       + lb[lane]);
  out[obase + lane + 64]  = f2bf((v1 - mean) * rstd * lw[lane + 64]  + lb[lane + 64]);
  out[obase + lane + 128] = f2bf((v2 - mean) * rstd * lw[lane + 128] + lb[lane + 128]);
}

// ---------------- LN2 (rows = x1 tokens then gt) ----------------
__global__ __launch_bounds__(256) void ln2_kernel(
    const float* __restrict__ resbuf,
    const float* __restrict__ lw, const float* __restrict__ lb,
    unsigned short* __restrict__ out)
{
  int row = blockIdx.x * 4 + (threadIdx.x >> 6);
  int lane = threadIdx.x & 63;
  const float* src = resbuf + (size_t)row * 192;
  float v0 = src[lane], v1 = src[lane + 64], v2 = src[lane + 128];
  float s = v0 + v1 + v2;
  float ss = v0 * v0 + v1 * v1 + v2 * v2;
  #pragma unroll
  for (int off = 32; off; off >>= 1) { s += __shfl_xor(s, off); ss += __shfl_xor(ss, off); }
  float mean = s * (1.0f / 192.0f);
  float var = ss * (1.0f / 192.0f) - mean * mean;
  float rstd = rsqrtf(var + 1e-5f);
  size_t obase = (size_t)row * 192;
  out[obase + lane]       = f2bf((v0 - mean) * rstd * lw[lane]       + lb[lane]);
  out[obase + lane + 64]  = f2bf((v1 - mean) * rstd * lw[lane + 64]  + lb[lane + 64]);
  out[obase + lane + 128] = f2bf((v2 - mean) * rstd * lw[lane + 128] + lb[lane + 128]);
}

// ---------------- GEMM: C[M x N] = A[M x K](bf16) @ BT[N x K]^T(bf16), tile 128x64, 4 waves ----------------
template<int MODE>
__global__ __launch_bounds__(256) void gemm_tpl(
    const unsigned short* __restrict__ A,
    const unsigned short* __restrict__ BT,
    const float* __restrict__ bias,
    unsigned short* __restrict__ outb,
    const float* __restrict__ xin,
    float* __restrict__ resbuf,
    float* __restrict__ dout,
    int N, int K)
{
  __shared__ unsigned short As[128][40];
  __shared__ unsigned short Bs[64][40];
  const int tid = threadIdx.x, lane = tid & 63, w = tid >> 6;
  const int wm = w >> 1, wn = w & 1;
  const int mbase = blockIdx.x * 128, nbase = blockIdx.y * 64;
  const int l15 = lane & 15, l4 = lane >> 4;

  f32x4 acc[4][2] = {};

  const int arow = tid >> 1, aseg = (tid & 1) * 16;
  const unsigned short* aptr = A + (size_t)(mbase + arow) * K + aseg;
  const int brow = tid >> 1;
  const unsigned short* bptr = BT + (size_t)(nbase + brow) * K + aseg;

  for (int kb = 0; kb < K; kb += 32) {
    int4 a0 = *reinterpret_cast<const int4*>(aptr + kb);
    int4 a1 = *reinterpret_cast<const int4*>(aptr + kb + 8);
    *reinterpret_cast<int4*>(&As[arow][aseg])     = a0;
    *reinterpret_cast<int4*>(&As[arow][aseg + 8]) = a1;
    if (tid < 128) {
      int4 b0 = *reinterpret_cast<const int4*>(bptr + kb);
      int4 b1 = *reinterpret_cast<const int4*>(bptr + kb + 8);
      *reinterpret_cast<int4*>(&Bs[brow][aseg])     = b0;
      *reinterpret_cast<int4*>(&Bs[brow][aseg + 8]) = b1;
    }
    __syncthreads();
    FragU af[4], bfr[2];
    #pragma unroll
    for (int mi = 0; mi < 4; mi++) {
      int r = wm * 64 + mi * 16 + l15;
      af[mi].h[0] = *reinterpret_cast<const bf16x4*>(&As[r][l4 * 4]);
      af[mi].h[1] = *reinterpret_cast<const bf16x4*>(&As[r][16 + l4 * 4]);
    }
    #pragma unroll
    for (int nj = 0; nj < 2; nj++) {
      int c = wn * 32 + nj * 16 + l15;
      bfr[nj].h[0] = *reinterpret_cast<const bf16x4*>(&Bs[c][l4 * 4]);
      bfr[nj].h[1] = *reinterpret_cast<const bf16x4*>(&Bs[c][16 + l4 * 4]);
    }
    #pragma unroll
    for (int mi = 0; mi < 4; mi++)
      #pragma unroll
      for (int nj = 0; nj < 2; nj++)
        acc[mi][nj] = __builtin_amdgcn_mfma_f32_16x16x32_bf16(af[mi].v, bfr[nj].v, acc[mi][nj], 0, 0, 0);
    __syncthreads();
  }

  #pragma unroll
  for (int mi = 0; mi < 4; mi++)
    #pragma unroll
    for (int nj = 0; nj < 2; nj++)
      #pragma unroll
      for (int reg = 0; reg < 4; reg++) {
        int r = mbase + wm * 64 + mi * 16 + l4 * 4 + reg;
        int c = nbase + wn * 32 + nj * 16 + l15;
        float v = acc[mi][nj][reg] + bias[c];
        if constexpr (MODE == 0) {
          if (c < 192) v *= SCALE_Q;
          outb[(size_t)r * N + c] = f2bf(v);
        } else if constexpr (MODE == 1) {
          int win = r / 99, t = r - win * 99;
          if (t == 0) {
            resbuf[(size_t)(XTOK + win) * 192 + c] = v;
          } else {
            int b = win >> 8, wi = win & 255;
            int wd = wi >> 6, wh = (wi >> 3) & 7, ww = wi & 7;
            int tt = t - 1, td = tt / 49, rr = tt - td * 49, th = rr / 7, tw = rr - th * 7;
            int d = (wd * 2 + td + 1) & 7;
            int h = wh * 7 + th + 3; if (h >= 56) h -= 56;
            int wc = ww * 7 + tw + 3; if (wc >= 56) wc -= 56;
            size_t idx = ((size_t)(((b * 8 + d) * 56 + h) * 56 + wc)) * 192 + c;
            resbuf[idx] = xin[idx] + v;
          }
        } else if constexpr (MODE == 2) {
          float g = 0.5f * v * (1.0f + erff(v * 0.70710678118654752f));
          outb[(size_t)r * N + c] = f2bf(g);
        } else {
          v += resbuf[(size_t)r * 192 + c];
          if (r < XTOK) dout[(size_t)r * 192 + c] = v;
          else dout[GT_OFF + (size_t)(r - XTOK) * 192 + c] = v;
        }
      }
}

// ---------------- attention, swapped-operand (S^T = K@Q^T), P fully in-register ----------------
// grid: blockIdx.x = head*512 + win  (same-win heads 512 apart -> same XCD -> qkv L2 reuse)
__global__ __launch_bounds__(256, 4) void attn_kernel(
    const unsigned short* __restrict__ qkv, // [50688][576] bf16 (q pre-scaled)
    const unsigned int* __restrict__ maskP, // [256][6336] packed transposed mask
    const unsigned int* __restrict__ rpbP,  // [6][6336] packed transposed rpb
    unsigned short* __restrict__ out)       // [50688][192] bf16
{
  const int win = blockIdx.x & 511;
  const int head = blockIdx.x >> 9;
  const int tid = threadIdx.x, lane = tid & 63, w = tid >> 6;
  const int l15 = lane & 15, l4 = (lane >> 4) & 3;

  __shared__ __align__(16) unsigned short Qs[128][40];
  __shared__ __align__(16) unsigned short Ks[128][40];
  __shared__ __align__(16) unsigned short VTs[32][136];

  const size_t rowbase = (size_t)win * 99;

  // ---- extra-table register preload (issued before staging; consumed after QK^T) ----
  const unsigned int* mkb = maskP + (size_t)(win & 255) * 6336;
  const unsigned int* rpb_ = rpbP + (size_t)head * 6336;
  const int q0 = w * 16 + l15;            // < 64, always valid
  const int q1 = 64 + q0;
  const int r1 = q1 < 99 ? q1 : 0;        // clamp padding rows
  unsigned int mk0[4][4], mk1[4][4], rp0[4][4], rp1[4][4];
  #pragma unroll
  for (int reg = 0; reg < 4; reg++)
    #pragma unroll
    for (int t = 0; t < 4; t++) {
      int boff = ((l4 * 4 + reg) * 4 + t) * 99;
      mk0[reg][t] = mkb[boff + q0];
      mk1[reg][t] = mkb[boff + r1];
      rp0[reg][t] = rpb_[boff + q0];
      rp1[reg][t] = rpb_[boff + r1];
    }

  // ---- stage Q, K (row-major) and V (transposed), coalesced global reads ----
  for (int idx = tid; idx < 512; idx += 256) {
    int r = idx >> 2, seg = (idx & 3) * 8;
    int4 zq = {0,0,0,0}, zk = {0,0,0,0}, zv = {0,0,0,0};
    if (r < 99) {
      const unsigned short* src = qkv + (rowbase + r) * 576 + head * 32 + seg;
      zq = *reinterpret_cast<const int4*>(src);
      zk = *reinterpret_cast<const int4*>(src + 192);
      zv = *reinterpret_cast<const int4*>(src + 384);
    }
    *reinterpret_cast<int4*>(&Qs[r][seg]) = zq;
    *reinterpret_cast<int4*>(&Ks[r][seg]) = zk;
    const unsigned short* pv = reinterpret_cast<const unsigned short*>(&zv);
    #pragma unroll
    for (int j = 0; j < 8; j++) VTs[seg + j][r] = pv[j];
  }
  __syncthreads();

  f32x4 oacc[2][2] = {};

  #pragma unroll
  for (int qi = 0; qi < 2; qi++) {
    const int qrow = qi * 64 + w * 16 + l15;
    FragU qf;
    qf.h[0] = *reinterpret_cast<const bf16x4*>(&Qs[qrow][l4 * 4]);
    qf.h[1] = *reinterpret_cast<const bf16x4*>(&Qs[qrow][16 + l4 * 4]);

    // S^T tiles: nj = k-token tile (k = nj*16 + l4*4 + reg); tile 7 (k>=112) always masked -> skipped
    f32x4 sacc[7] = {};
    #pragma unroll
    for (int nj = 0; nj < 7; nj++) {
      FragU kf;
      kf.h[0] = *reinterpret_cast<const bf16x4*>(&Ks[nj * 16 + l15][l4 * 4]);
      kf.h[1] = *reinterpret_cast<const bf16x4*>(&Ks[nj * 16 + l15][16 + l4 * 4]);
      sacc[nj] = __builtin_amdgcn_mfma_f32_16x16x32_bf16(kf.v, qf.v, sacc[nj], 0, 0, 0);
    }

    // ---- softmax fully in-register (row q = l15; k spread over l4 x reg x nj) ----
    float m = -1e30f;
    #pragma unroll
    for (int nj = 0; nj < 7; nj++) {
      int t = nj >> 1;
      #pragma unroll
      for (int reg = 0; reg < 4; reg++) {
        unsigned int mu = qi ? mk1[reg][t] : mk0[reg][t];
        unsigned int ru = qi ? rp1[reg][t] : rp0[reg][t];
        unsigned int mb = (nj & 1) ? (mu & 0xFFFF0000u) : (mu << 16);
        unsigned int rb = (nj & 1) ? (ru & 0xFFFF0000u) : (ru << 16);
        float s = sacc[nj][reg] + __uint_as_float(mb) + __uint_as_float(rb);
        if (nj == 6 && (96 + l4 * 4 + reg) >= 99) s = -1e30f;
        sacc[nj][reg] = s;
        m = fmaxf(m, s);
      }
    }
    m = fmaxf(m, __shfl_xor(m, 16));
    m = fmaxf(m, __shfl_xor(m, 32));
    float sum = 0.0f;
    #pragma unroll
    for (int nj = 0; nj < 7; nj++)
      #pragma unroll
      for (int reg = 0; reg < 4; reg++) {
        float e = __expf(sacc[nj][reg] - m);
        sacc[nj][reg] = e;
        sum += e;
      }
    sum += __shfl_xor(sum, 16);
    sum += __shfl_xor(sum, 32);
    const float inv = 1.0f / sum;

    // ---- PV: S^T acc layout == A-fragment layout, build pa in-lane ----
    #pragma unroll
    for (int ks = 0; ks < 4; ks++) {
      union { unsigned short u[8]; bf16x8 v; } pa;
      #pragma unroll
      for (int j = 0; j < 4; j++) {
        pa.u[j] = f2bf(sacc[2 * ks][j] * inv);
        pa.u[4 + j] = (ks == 3) ? (unsigned short)0 : f2bf(sacc[2 * ks + 1][j] * inv);
      }
      #pragma unroll
      for (int njd = 0; njd < 2; njd++) {
        FragU vb;
        vb.h[0] = *reinterpret_cast<const bf16x4*>(&VTs[njd * 16 + l15][ks * 32 + l4 * 4]);
        vb.h[1] = *reinterpret_cast<const bf16x4*>(&VTs[njd * 16 + l15][ks * 32 + 16 + l4 * 4]);
        oacc[qi][njd] = __builtin_amdgcn_mfma_f32_16x16x32_bf16(pa.v, vb.v, oacc[qi][njd], 0, 0, 0);
      }
    }
  }

  // ---- store: PV D layout col=l15=d, row=l4*4+reg=q-within-16 ----
  #pragma unroll
  for (int qi = 0; qi < 2; qi++)
    #pragma unroll
    for (int njd = 0; njd < 2; njd++)
      #pragma unroll
      for (int reg = 0; reg < 4; reg++) {
        int q = qi * 64 + w * 16 + l4 * 4 + reg;
        if (q < 99)
          out[(rowbase + q) * 192 + head * 32 + njd * 16 + l15] = f2bf(oacc[qi][njd][reg]);
      }
}

// ---------------- host ----------------
extern "C" void kernel_launch(void* const* d_in, const int* in_sizes, int n_in,
                              void* d_out, int out_size, void* d_ws, size_t ws_size,
                              hipStream_t stream) {
  (void)in_sizes; (void)n_in; (void)out_size; (void)ws_size;
  const float* x     = (const float*)d_in[0];
  const float* gtok  = (const float*)d_in[1];
  // d_in[2] = position (unused by reference)
  const float* amask = (const float*)d_in[3];
  const float* n1w   = (const float*)d_in[4];
  const float* n1b   = (const float*)d_in[5];
  const float* qkvw  = (const float*)d_in[6];
  const float* qkvb  = (const float*)d_in[7];
  const float* projw = (const float*)d_in[8];
  const float* projb = (const float*)d_in[9];
  const float* rpb   = (const float*)d_in[10];
  const float* n2w   = (const float*)d_in[11];
  const float* n2b   = (const float*)d_in[12];
  const float* fc1w  = (const float*)d_in[13];
  const float* fc1b  = (const float*)d_in[14];
  const float* fc2w  = (const float*)d_in[15];
  const float* fc2b  = (const float*)d_in[16];

  char* ws = (char*)d_ws;
  unsigned short* wbuf = (unsigned short*)ws;              // 442368 bf16 weights (transposed)
  unsigned short* X    = (unsigned short*)(ws + 884736);   // 50688x192 bf16 (xw -> attn_out -> ln2)
  unsigned short* Qb   = (unsigned short*)(ws + 20348928); // 50688x576 bf16 qkv, then 50688x768 bf16 h
  float*          Rb   = (float*)(ws + 98205696);          // 50688x192 fp32 (x1 tokens + gt rows)
  unsigned int*   maskP= (unsigned int*)(ws + 98205696);   // 256x6336 u32 — aliases Rb (dead before MODE1)
  unsigned int*   rpbP = (unsigned int*)(ws + 104693760);  // 6x6336 u32  — aliases Rb (dead before MODE1)
  float* dout = (float*)d_out;

  prep_w<<<1728, 256, 0, stream>>>(qkvw, projw, fc1w, fc2w, wbuf);
  prep_maskT<<<256, 256, 0, stream>>>(amask, maskP);
  prep_rpbT<<<149, 256, 0, stream>>>(rpb, rpbP);
  ln1_kernel<<<12672, 256, 0, stream>>>(x, gtok, n1w, n1b, X);
  gemm_tpl<0><<<dim3(396, 9), 256, 0, stream>>>(X, wbuf, qkvb, Qb, nullptr, nullptr, nullptr, 576, 192);
  attn_kernel<<<3072, 256, 0, stream>>>(Qb, maskP, rpbP, X);
  gemm_tpl<1><<<dim3(396, 3), 256, 0, stream>>>(X, wbuf + 110592, projb, nullptr, x, Rb, nullptr, 192, 192);
  ln2_kernel<<<12672, 256, 0, stream>>>(Rb, n2w, n2b, X);
  gemm_tpl<2><<<dim3(396, 12), 256, 0, stream>>>(X, wbuf + 147456, fc1b, Qb, nullptr, nullptr, nullptr, 768, 192);
  gemm_tpl<3><<<dim3(396, 3), 256, 0, stream>>>(Qb, wbuf + 294912, fc2b, nullptr, nullptr, Rb, dout, 192, 768);
}